// Round 1
// baseline (84.404 us; speedup 1.0000x reference)
//
#include <hip/hip_runtime.h>
#include <math.h>

#define NW 16
#define NEUR 32
#define TTAB 8192            // global F-table nodes over [0,1]
#define WSUB 0.0625f         // 1/16, exact in fp32
#define INV_SIGMA 200.0f     // 1/0.005
#define OMEGA 15.0f
#define WTHRESH 1e-5f
#define EVAL_BLOCKS 512
#define EVAL_THREADS 256

__device__ __forceinline__ float sigmoid_f(float z) {
    return 1.0f / (1.0f + __expf(-z));
}
__device__ __forceinline__ float tanh_fast(float z) {
    // z bounded here; tanh = 1 - 2/(e^{2z}+1)
    const float e = __expf(2.0f * z);
    return 1.0f - 2.0f / (e + 1.0f);
}

// win_c(x) * u_c(x) for window c (full MLP), 0 if masked/out-of-range.
// Register-lean: layer-2 computed 4 outputs at a time and consumed
// immediately into the W3 dot product -> ~45 live floats, no spill.
__device__ __forceinline__ float window_term(
    float x, int c,
    const float* __restrict__ W1, const float* __restrict__ b1,
    const float* __restrict__ W2, const float* __restrict__ b2,
    const float* __restrict__ W3, const float* __restrict__ b3) {
    if (c < 0 || c >= NW) return 0.0f;
    const float s1 = sigmoid_f((x - (float)c * WSUB) * INV_SIGMA);
    const float s2 = sigmoid_f(-(x - (float)(c + 1) * WSUB) * INV_SIGMA);
    const float win = s1 * s2;
    if (win <= WTHRESH) return 0.0f;

    // subdomain normalization constants (exact dyadic, match reference fp64->fp32)
    float mean, sd;
    if (c == 0)            { mean = 0.03515625f; sd = 0.03515625f; }
    else if (c == NW - 1)  { mean = 0.96484375f; sd = 0.03515625f; }
    else                   { mean = ((float)c + 0.5f) * 0.0625f; sd = 0.0390625f; }
    const float xn = (x - mean) / sd;

    const float* __restrict__ W1c = W1 + c * NEUR;
    const float* __restrict__ b1c = b1 + c * NEUR;
    float h1[NEUR];
#pragma unroll
    for (int j = 0; j < NEUR; ++j)
        h1[j] = tanh_fast(fmaf(xn, W1c[j], b1c[j]));

    const float* __restrict__ W2c = W2 + c * NEUR * NEUR;  // [k][j]
    const float* __restrict__ b2c = b2 + c * NEUR;
    const float* __restrict__ W3c = W3 + c * NEUR;
    float acc = b3[c];
#pragma unroll
    for (int j = 0; j < NEUR; j += 4) {
        float a0 = b2c[j], a1 = b2c[j + 1], a2 = b2c[j + 2], a3 = b2c[j + 3];
#pragma unroll
        for (int k = 0; k < NEUR; ++k) {
            const float hk = h1[k];
            const float4 wv = *(const float4*)(W2c + k * NEUR + j);
            a0 = fmaf(hk, wv.x, a0);
            a1 = fmaf(hk, wv.y, a1);
            a2 = fmaf(hk, wv.z, a2);
            a3 = fmaf(hk, wv.w, a3);
        }
        acc = fmaf(tanh_fast(a0), W3c[j],     acc);
        acc = fmaf(tanh_fast(a1), W3c[j + 1], acc);
        acc = fmaf(tanh_fast(a2), W3c[j + 2], acc);
        acc = fmaf(tanh_fast(a3), W3c[j + 3], acc);
    }

    return win * acc;   // U_SD=1, U_MEAN=0
}

// ---------- K1: build pre-summed F table. 128 blocks x 192 threads ----------
// wave w = d (window offset), lane l = node within block's 64-node span.
__global__ __launch_bounds__(192) void build_F(
    const float* __restrict__ W1, const float* __restrict__ b1,
    const float* __restrict__ W2, const float* __restrict__ b2,
    const float* __restrict__ W3, const float* __restrict__ b3,
    float* __restrict__ F_ws) {
    __shared__ float partial[3][64];
    const int t = threadIdx.x;
    const int d = t >> 6;          // 0,1,2 (wave-uniform)
    const int l = t & 63;
    const int g = blockIdx.x * 64 + l;

    const float xg = (float)g * (1.0f / (float)(TTAB - 1));
    int i0 = (int)(xg * 16.0f);
    if (i0 > NW - 1) i0 = NW - 1;
    partial[d][l] = window_term(xg, i0 - 1 + d, W1, b1, W2, b2, W3, b3);
    __syncthreads();
    if (t < 64)
        F_ws[g] = partial[0][l] + partial[1][l] + partial[2][l];
}

// ---------- K2: stage F into LDS; per point one lerp + tanh(15x) ----------
__global__ __launch_bounds__(EVAL_THREADS) void eval_F(
    const float* __restrict__ x, const float* __restrict__ F_ws,
    float* __restrict__ out, int n) {
    __shared__ float F[TTAB];   // 32 KB

#if defined(__HIP_DEVICE_COMPILE__)
    {
        // Async direct-to-LDS staging: 4 waves x 8 chunks x 1 KiB = 32 KiB.
        // LDS dest is wave-uniform base; HW writes lane l at dst + l*16 ->
        // linear layout preserved.
        const int wave = threadIdx.x >> 6;
        const int lane = threadIdx.x & 63;
#pragma unroll
        for (int i = 0; i < 8; ++i) {
            const int chunk = wave * 8 + i;                // 0..31
            const float* gsrc = F_ws + chunk * 256 + lane * 4;
            __builtin_amdgcn_global_load_lds(
                (const __attribute__((address_space(1))) void*)gsrc,
                (__attribute__((address_space(3))) void*)(&F[chunk * 256]),
                16, 0, 0);
        }
    }
#else
    {
        const float4* __restrict__ src = (const float4*)F_ws;
        float4* dst = (float4*)F;
        for (int i = threadIdx.x; i < TTAB / 4; i += EVAL_THREADS)
            dst[i] = src[i];
    }
#endif
    __syncthreads();   // drains vmcnt -> staging complete

    const int n4 = n >> 2;
    const int stride = gridDim.x * blockDim.x;
    for (int idx = blockIdx.x * blockDim.x + threadIdx.x; idx < n4; idx += stride) {
        const float4 xv = *(const float4*)(x + idx * 4);
        float4 r;
#pragma unroll
        for (int e = 0; e < 4; ++e) {
            const float xe = (&xv.x)[e];
            float tt = xe * (float)(TTAB - 1);
            tt = fminf(fmaxf(tt, 0.0f), (float)(TTAB - 1) - 0.5f);
            const int it = (int)tt;
            const float f = tt - (float)it;
            const float u0 = F[it];
            const float u1 = F[it + 1];
            const float u = fmaf(f, u1 - u0, u0);
            (&r.x)[e] = tanh_fast(OMEGA * xe) * u;
        }
        *(float4*)(out + idx * 4) = r;
    }
    if (blockIdx.x == 0) {
        const int tail = n & 3;
        if ((int)threadIdx.x < tail) {
            const float xe = x[n4 * 4 + threadIdx.x];
            float tt = xe * (float)(TTAB - 1);
            tt = fminf(fmaxf(tt, 0.0f), (float)(TTAB - 1) - 0.5f);
            const int it = (int)tt;
            const float f = tt - (float)it;
            const float u = fmaf(f, F[it + 1] - F[it], F[it]);
            out[n4 * 4 + threadIdx.x] = tanh_fast(OMEGA * xe) * u;
        }
    }
}

extern "C" void kernel_launch(void* const* d_in, const int* in_sizes, int n_in,
                              void* d_out, int out_size, void* d_ws, size_t ws_size,
                              hipStream_t stream) {
    const float* x  = (const float*)d_in[0];
    const float* W1 = (const float*)d_in[1];
    const float* b1 = (const float*)d_in[2];
    const float* W2 = (const float*)d_in[3];
    const float* b2 = (const float*)d_in[4];
    const float* W3 = (const float*)d_in[5];
    const float* b3 = (const float*)d_in[6];
    float* out = (float*)d_out;
    float* F_ws = (float*)d_ws;   // TTAB floats = 32 KB
    const int n = in_sizes[0];

    build_F<<<TTAB / 64, 192, 0, stream>>>(W1, b1, W2, b2, W3, b3, F_ws);
    eval_F<<<EVAL_BLOCKS, EVAL_THREADS, 0, stream>>>(x, F_ws, out, n);
}